// Round 8
// baseline (1952.864 us; speedup 1.0000x reference)
//
#include <hip/hip_runtime.h>
#include <hip/hip_bf16.h>

#define S_LEN 2048
#define BATCH 8
#define HID   1024
#define NP    3072      // permuted gate dim: i,g,o only (f is dead in reference)
#define MROWS 16384     // S*B

using bf16x8 = __attribute__((ext_vector_type(8))) short;
using f32x16 = __attribute__((ext_vector_type(16))) float;

__device__ __forceinline__ unsigned short f2b(float f) {
  unsigned int u = __builtin_bit_cast(unsigned int, f);
  u += 0x7fffu + ((u >> 16) & 1u);   // RNE
  return (unsigned short)(u >> 16);
}

__device__ __forceinline__ float sigf(float x) {
  return 1.f / (1.f + __expf(-x));
}
__device__ __forceinline__ float tanh_f(float x) {
  return 2.f / (1.f + __expf(-2.f * x)) - 1.f;   // exact limits at +-inf
}

__device__ __forceinline__ void load_lds16(const void* g, void* l) {
  __builtin_amdgcn_global_load_lds(
      (const __attribute__((address_space(1))) void*)g,
      (__attribute__((address_space(3))) void*)(unsigned int)(unsigned long long)l,
      16, 0, 0);
}

#define MEMFENCE asm volatile("" ::: "memory")
#define BARRIER  do { MEMFENCE; __builtin_amdgcn_s_barrier(); MEMFENCE; } while (0)
#define SCHED0   __builtin_amdgcn_sched_barrier(0)

// ---- weight fragment-pack (device helper). Same layout as R7 (verified).
__device__ __forceinline__ void pack_w_dev(const float* __restrict__ W,
                                           unsigned short* __restrict__ Wp,
                                           int id, int Kshift, int ntshift) {
  const int l = id & 63;
  const int q = id >> 6;
  const int c = q % 24;
  const int q24 = q / 24;
  const int t  = q24 & ((1 << ntshift) - 1);
  const int bn = q24 >> ntshift;
  const int nf = c >> 1, ks = c & 1;
  const int gate = nf % 3, hgrp = nf / 3;
  const int og = (gate == 0) ? 0 : (gate == 1) ? 2 : 3;
  const int row = og * 1024 + (bn * 4 + hgrp) * 32 + (l & 31);
  const int k   = t * 32 + ks * 16 + (l >> 5) * 8;
  const float* s = W + ((long)row << Kshift) + k;
  const float4 v0 = *reinterpret_cast<const float4*>(s);
  const float4 v1 = *reinterpret_cast<const float4*>(s + 4);
  uint4 o;
  o.x = (unsigned)f2b(v0.x) | ((unsigned)f2b(v0.y) << 16);
  o.y = (unsigned)f2b(v0.z) | ((unsigned)f2b(v0.w) << 16);
  o.z = (unsigned)f2b(v1.x) | ((unsigned)f2b(v1.y) << 16);
  o.w = (unsigned)f2b(v1.z) | ((unsigned)f2b(v1.w) << 16);
  *reinterpret_cast<uint4*>(Wp + (long)id * 8) = o;
}

// ---- single fused prep kernel: x cvt + 4 weight packs + 4 bias packs ----
__global__ void prep(const float* __restrict__ x, unsigned short* __restrict__ x_bf,
                     const float* __restrict__ Wf0, const float* __restrict__ Wb0,
                     const float* __restrict__ Wf1, const float* __restrict__ Wb1,
                     unsigned short* __restrict__ pf0, unsigned short* __restrict__ pb0,
                     unsigned short* __restrict__ pf1, unsigned short* __restrict__ pb1,
                     const float* __restrict__ bf0, const float* __restrict__ bb0,
                     const float* __restrict__ bf1, const float* __restrict__ bb1,
                     float* __restrict__ bpf0, float* __restrict__ bpb0,
                     float* __restrict__ bpf1, float* __restrict__ bpb1) {
  const int blk = blockIdx.x;
  const int tid = threadIdx.x;
  if (blk < 16384) {               // x: fp32 -> bf16, float4/thread (exact)
    const int i = blk * 256 + tid;
    const float4 v = reinterpret_cast<const float4*>(x)[i];
    ushort4 u;
    u.x = f2b(v.x); u.y = f2b(v.y); u.z = f2b(v.z); u.w = f2b(v.w);
    reinterpret_cast<ushort4*>(x_bf)[i] = u;
  } else if (blk < 17920) {
    pack_w_dev(Wf0, pf0, (blk - 16384) * 256 + tid, 10, 5);
  } else if (blk < 19456) {
    pack_w_dev(Wb0, pb0, (blk - 17920) * 256 + tid, 10, 5);
  } else if (blk < 22528) {
    pack_w_dev(Wf1, pf1, (blk - 19456) * 256 + tid, 11, 6);
  } else if (blk < 25600) {
    pack_w_dev(Wb1, pb1, (blk - 22528) * 256 + tid, 11, 6);
  } else {                         // biases: np = c32*96 + gate*32 + hl
    const int r = blk - 25600;     // 0..47
    const int which = r / 12;
    const int np = (r % 12) * 256 + tid;
    const float* bs = which == 0 ? bf0 : which == 1 ? bb0 : which == 2 ? bf1 : bb1;
    float* bd       = which == 0 ? bpf0 : which == 1 ? bpb0 : which == 2 ? bpf1 : bpb1;
    const int c32 = np / 96, rem = np % 96;
    const int gate = rem >> 5, hl = rem & 31;
    const int og = (gate == 0) ? 0 : (gate == 1) ? 2 : 3;
    bd[np] = bs[og * 1024 + c32 * 32 + hl];
  }
}

// ---- fused GEMM + gates. Fragment-linear LDS (0-conflict, R7-verified) +
//  phase-pipelined schedule: 2 phases per BK=32 tile, 12 MFMA each; each
//  phase issues NEXT phase's 7 ds_reads before its MFMA cluster; stage into
//  3rd rotating buffer; steady-state wait = vmcnt(3) once/tile (counted,
//  targets loads issued one full tile earlier). Block 256x384, 8 waves
//  (2Mx4N), wave tile 128x96 of 32x32x16. LDS 3 x 40KB. ----
#define MFMAOP(a_, b_, c_) \
  c_ = __builtin_amdgcn_mfma_f32_32x32x16_bf16(a_, b_, c_, 0, 0, 0)

#define READS(P, KS, A0_,A1_,A2_,A3_, B0_,B1_,B2_) do {           \
    A0_ = *(const bf16x8*)((P) + abase_r          + (KS)*1024);   \
    A1_ = *(const bf16x8*)((P) + abase_r + 2048   + (KS)*1024);   \
    A2_ = *(const bf16x8*)((P) + abase_r + 4096   + (KS)*1024);   \
    A3_ = *(const bf16x8*)((P) + abase_r + 6144   + (KS)*1024);   \
    B0_ = *(const bf16x8*)((P) + bbase_r          + (KS)*1024);   \
    B1_ = *(const bf16x8*)((P) + bbase_r + 2048   + (KS)*1024);   \
    B2_ = *(const bf16x8*)((P) + bbase_r + 4096   + (KS)*1024);   \
  } while (0)

#define MF12(A0_,A1_,A2_,A3_, B0_,B1_,B2_) do {                   \
    __builtin_amdgcn_s_setprio(1);                                \
    MFMAOP(A0_,B0_,acc[0][0]); MFMAOP(A1_,B0_,acc[1][0]);         \
    MFMAOP(A2_,B0_,acc[2][0]); MFMAOP(A3_,B0_,acc[3][0]);         \
    MFMAOP(A0_,B1_,acc[0][1]); MFMAOP(A1_,B1_,acc[1][1]);         \
    MFMAOP(A2_,B1_,acc[2][1]); MFMAOP(A3_,B1_,acc[3][1]);         \
    MFMAOP(A0_,B2_,acc[0][2]); MFMAOP(A1_,B2_,acc[1][2]);         \
    MFMAOP(A2_,B2_,acc[2][2]); MFMAOP(A3_,B2_,acc[3][2]);         \
    __builtin_amdgcn_s_setprio(0);                                \
  } while (0)

#define STG0(T, DB) do {                                          \
    const long ta_ = (long)(T) * 64;                              \
    const long tb_ = (long)(T) * 24576;                           \
    load_lds16(srcA0 + ta_, (DB) + dA0);                          \
    load_lds16(srcA1 + ta_, (DB) + dA1);                          \
    load_lds16(srcB  + tb_, (DB) + dB0);                          \
  } while (0)
#define STG1(T, DB) do {                                          \
    const long tb_ = (long)(T) * 24576;                           \
    load_lds16(srcB + tb_ + 8192,  (DB) + dB0 + 8192);            \
    load_lds16(srcB + tb_ + 16384, (DB) + dB0 + 16384);           \
  } while (0)

template <int MODE>  // 0: layer0 (bf16 out), 1: layer1 (fp32 out to d_out)
__global__ void __launch_bounds__(512, 2)
lstm_gemm(const unsigned short* __restrict__ A,
          const unsigned short* __restrict__ PF,
          const unsigned short* __restrict__ PB,
          const float* __restrict__ bpF, const float* __restrict__ bpB,
          int K,
          unsigned short* __restrict__ out_bf, float* __restrict__ out_f,
          float* __restrict__ hn, float* __restrict__ cn) {
  __shared__ __align__(16) char lds[122880];   // 3 x 40960

  const int dir = blockIdx.z;
  const unsigned short* __restrict__ Wp = dir ? PB : PF;
  const float* __restrict__ bp = dir ? bpB : bpF;

  // XCD swizzle: 8 consecutive dispatch ids = 8 XCDs get 8 DIFFERENT bm;
  // each XCD then walks all 8 bn of its bm -> A-panel L2-resident per XCD.
  const int dflat = blockIdx.x + (blockIdx.y << 3);   // 0..511
  const int bm = (dflat & 7) + ((dflat >> 6) << 3);   // 0..63
  const int bn = (dflat >> 3) & 7;                    // 0..7

  const int tid  = threadIdx.x;
  const int wid  = tid >> 6;   // 0..7
  const int lane = tid & 63;
  const int wm   = wid >> 2;   // 0..1
  const int wn   = wid & 3;    // 0..3
  const int l31  = lane & 31;
  const int b5   = lane >> 5;

  const int  nt = K >> 5;      // BK=32
  const long K2 = (long)K * 2;

  // staging sources (fragment-gather for A; packed-linear for B)
  const char* srcA0 = (const char*)A + ((long)(bm * 256 + (wid >> 1) * 32 + l31)) * K2
                      + (wid & 1) * 32 + b5 * 16;
  const char* srcA1 = (const char*)A + ((long)(bm * 256 + ((wid + 8) >> 1) * 32 + l31)) * K2
                      + ((wid + 8) & 1) * 32 + b5 * 16;
  const char* srcB  = (const char*)Wp + (long)bn * nt * 24576 + wid * 1024 + lane * 16;
  const int dA0 = wid * 1024;
  const int dA1 = (wid + 8) * 1024;
  const int dB0 = 16384 + wid * 1024;

  // compute-side chunk bases (linear: + lane*16)
  const int abase_r = wm * 8192 + lane * 16;           // + mf*2048 + ks*1024
  const int bbase_r = 16384 + wn * 6144 + lane * 16;   // + nf*2048 + ks*1024

  f32x16 acc[4][3];
#pragma unroll
  for (int i = 0; i < 4; ++i)
#pragma unroll
    for (int j = 0; j < 3; ++j)
      acc[i][j] = (f32x16)(0.f);

  char* p0 = lds;
  char* p1 = lds + 40960;
  char* p2 = lds + 81920;

  bf16x8 eA0, eA1, eA2, eA3, eB0, eB1, eB2;
  bf16x8 oA0, oA1, oA2, oA3, oB0, oB1, oB2;

  // prologue: tiles 0,1 staged; read E = (0, ks0)
  STG0(0, p0); STG1(0, p0);
  STG0(1, p1); STG1(1, p1);
  asm volatile("s_waitcnt vmcnt(5)" ::: "memory");   // tile 0 resident
  SCHED0;
  BARRIER;
  READS(p0, 0, eA0, eA1, eA2, eA3, eB0, eB1, eB2);

#pragma unroll 1
  for (int t = 0; t < nt - 2; ++t) {
    // phase 0: prefetch O=(t,ks1); stage half of t+2; MFMA on E=(t,ks0)
    READS(p0, 1, oA0, oA1, oA2, oA3, oB0, oB1, oB2);
    STG0(t + 2, p2);
    asm volatile("s_waitcnt vmcnt(3)" ::: "memory");  // t+1 resident; keep 3
    SCHED0;
    BARRIER;
    SCHED0;
    MF12(eA0, eA1, eA2, eA3, eB0, eB1, eB2);
    SCHED0;
    BARRIER;
    // phase 1: prefetch E=(t+1,ks0); stage rest of t+2; MFMA on O
    READS(p1, 0, eA0, eA1, eA2, eA3, eB0, eB1, eB2);
    STG1(t + 2, p2);
    SCHED0;
    BARRIER;
    SCHED0;
    MF12(oA0, oA1, oA2, oA3, oB0, oB1, oB2);
    SCHED0;
    BARRIER;
    char* tp = p0; p0 = p1; p1 = p2; p2 = tp;
  }

  // tile nt-2 (no staging; one-time full drain)
  READS(p0, 1, oA0, oA1, oA2, oA3, oB0, oB1, oB2);
  asm volatile("s_waitcnt vmcnt(0)" ::: "memory");
  SCHED0;
  BARRIER;
  SCHED0;
  MF12(eA0, eA1, eA2, eA3, eB0, eB1, eB2);
  SCHED0;
  BARRIER;
  READS(p1, 0, eA0, eA1, eA2, eA3, eB0, eB1, eB2);
  SCHED0;
  BARRIER;
  SCHED0;
  MF12(oA0, oA1, oA2, oA3, oB0, oB1, oB2);
  SCHED0;
  BARRIER;
  { char* tp = p0; p0 = p1; p1 = p2; p2 = tp; }

  // tile nt-1
  READS(p0, 1, oA0, oA1, oA2, oA3, oB0, oB1, oB2);
  SCHED0;
  BARRIER;
  SCHED0;
  MF12(eA0, eA1, eA2, eA3, eB0, eB1, eB2);
  MF12(oA0, oA1, oA2, oA3, oB0, oB1, oB2);

  // ---- epilogue: gates -> h (and h_n/c_n rows).
  //  C layout (32x32): col = lane&31, row = (r&3) + 8*(r>>2) + 4*(lane>>5).
  const int c32  = bn * 4 + wn;          // 32-wide h-chunk
  const int h    = c32 * 32 + l31;
  const int outcol = dir * HID + h;
  const float bi = bp[c32 * 96 + l31];
  const float bg = bp[c32 * 96 + 32 + l31];
  const float bo = bp[c32 * 96 + 64 + l31];
  const int Lidx = MODE * 2 + dir;
  const int mrow0 = bm * 256 + wm * 128 + b5 * 4;

#pragma unroll
  for (int mf = 0; mf < 4; ++mf) {
#pragma unroll
    for (int r = 0; r < 16; ++r) {
      const int m = mrow0 + mf * 32 + (r & 3) + 8 * (r >> 2);
      const float iv = acc[mf][0][r] + bi;
      const float gv = acc[mf][1][r] + bg;
      const float ov = acc[mf][2][r] + bo;
      const float is = sigf(iv);
      const float gt = tanh_f(gv);
      const float os = sigf(ov);
      const float c  = is * gt;
      const float hv = os * tanh_f(c);
      if (MODE == 0) {
        out_bf[(long)m * 2048 + outcol] = f2b(hv);
      } else {
        out_f[(long)m * 2048 + outcol] = hv;
      }
      const bool wst = (dir == 0) ? (m >= (S_LEN - 1) * BATCH) : (m < BATCH);
      if (wst) {
        const int b = (dir == 0) ? (m - (S_LEN - 1) * BATCH) : m;
        hn[((long)Lidx * BATCH + b) * HID + h] = hv;
        cn[((long)Lidx * BATCH + b) * HID + h] = c;
      }
    }
  }
}

extern "C" void kernel_launch(void* const* d_in, const int* in_sizes, int n_in,
                              void* d_out, int out_size, void* d_ws, size_t ws_size,
                              hipStream_t stream) {
  const float* x    = (const float*)d_in[0];
  const float* W_f0 = (const float*)d_in[1];
  const float* b_f0 = (const float*)d_in[2];
  const float* W_b0 = (const float*)d_in[3];
  const float* b_b0 = (const float*)d_in[4];
  const float* W_f1 = (const float*)d_in[5];
  const float* b_f1 = (const float*)d_in[6];
  const float* W_b1 = (const float*)d_in[7];
  const float* b_b1 = (const float*)d_in[8];

  float* out = (float*)d_out;
  float* hn  = out + (long)MROWS * 2048;
  float* cn  = hn + 4 * BATCH * HID;

  unsigned short* x_bf  = (unsigned short*)d_ws;
  unsigned short* out1  = x_bf + (long)MROWS * 1024;
  unsigned short* wp_f0 = out1 + (long)MROWS * 2048;
  unsigned short* wp_b0 = wp_f0 + (long)NP * 1024;
  unsigned short* wp_f1 = wp_b0 + (long)NP * 1024;
  unsigned short* wp_b1 = wp_f1 + (long)NP * 2048;
  float* bp_f0 = (float*)(wp_b1 + (long)NP * 2048);
  float* bp_b0 = bp_f0 + NP;
  float* bp_f1 = bp_b0 + NP;
  float* bp_b1 = bp_f1 + NP;

  prep<<<25648, 256, 0, stream>>>(x, x_bf, W_f0, W_b0, W_f1, W_b1,
                                  wp_f0, wp_b0, wp_f1, wp_b1,
                                  b_f0, b_b0, b_f1, b_b1,
                                  bp_f0, bp_b0, bp_f1, bp_b1);

  dim3 grid(NP / 384, MROWS / 256, 2);
  lstm_gemm<0><<<grid, 512, 0, stream>>>(x_bf, wp_f0, wp_b0, bp_f0, bp_b0, 1024,
                                         out1, nullptr, hn, cn);
  lstm_gemm<1><<<grid, 512, 0, stream>>>(out1, wp_f1, wp_b1, bp_f1, bp_b1, 2048,
                                         nullptr, out, hn, cn);
}

// Round 9
// 650.215 us; speedup vs baseline: 3.0034x; 3.0034x over previous
//
#include <hip/hip_runtime.h>
#include <hip/hip_bf16.h>

#define S_LEN 2048
#define BATCH 8
#define HID   1024
#define NP    3072      // permuted gate dim: i,g,o only (f is dead in reference)
#define MROWS 16384     // S*B

using bf16x8 = __attribute__((ext_vector_type(8))) short;
using f32x4  = __attribute__((ext_vector_type(4))) float;

__device__ __forceinline__ unsigned short f2b(float f) {
  unsigned int u = __builtin_bit_cast(unsigned int, f);
  u += 0x7fffu + ((u >> 16) & 1u);   // RNE
  return (unsigned short)(u >> 16);
}

__device__ __forceinline__ float sigf(float x) {
  return 1.f / (1.f + __expf(-x));
}
__device__ __forceinline__ float tanh_f(float x) {
  return 2.f / (1.f + __expf(-2.f * x)) - 1.f;   // exact limits at +-inf
}

__device__ __forceinline__ void load_lds16(const void* g, void* l) {
  __builtin_amdgcn_global_load_lds(
      (const __attribute__((address_space(1))) void*)g,
      (__attribute__((address_space(3))) void*)(unsigned int)(unsigned long long)l,
      16, 0, 0);
}

#define MEMFENCE asm volatile("" ::: "memory")
#define BARRIER  do { MEMFENCE; __builtin_amdgcn_s_barrier(); MEMFENCE; } while (0)

// ---- fused prep: x cvt + 4 weight permutes + 4 bias permutes (one launch).
//  Weight layout (R3-verified): Wp[np][k], np = chunk*48 + gate3*16 + hl,
//  gate3 {0:i,1:g,2:o} -> orig rows {0,2,3}*1024 + chunk*16 + hl. ----
__device__ __forceinline__ void permute_w_dev(const float* __restrict__ W,
                                              unsigned short* __restrict__ Wp,
                                              long id, int K) {
  const long i = id * 4;
  const int np = (int)(i / K);
  const int k0 = (int)(i % K);
  const int chunk = np / 48, rem = np % 48;
  const int g3 = rem >> 4, hl = rem & 15;
  const int og = (g3 == 0) ? 0 : (g3 == 1) ? 2 : 3;
  const int n  = og * 1024 + chunk * 16 + hl;
  const float4 v = *reinterpret_cast<const float4*>(W + (long)n * K + k0);
  ushort4 u;
  u.x = f2b(v.x); u.y = f2b(v.y); u.z = f2b(v.z); u.w = f2b(v.w);
  *reinterpret_cast<ushort4*>(Wp + i) = u;
}

__global__ void prep(const float* __restrict__ x, unsigned short* __restrict__ x_bf,
                     const float* __restrict__ Wf0, const float* __restrict__ Wb0,
                     const float* __restrict__ Wf1, const float* __restrict__ Wb1,
                     unsigned short* __restrict__ pf0, unsigned short* __restrict__ pb0,
                     unsigned short* __restrict__ pf1, unsigned short* __restrict__ pb1,
                     const float* __restrict__ bf0, const float* __restrict__ bb0,
                     const float* __restrict__ bf1, const float* __restrict__ bb1,
                     float* __restrict__ bpf0, float* __restrict__ bpb0,
                     float* __restrict__ bpf1, float* __restrict__ bpb1) {
  const int blk = blockIdx.x;
  const int tid = threadIdx.x;
  if (blk < 16384) {               // x: fp32 -> bf16, float4/thread (exact)
    const int i = blk * 256 + tid;
    const float4 v = reinterpret_cast<const float4*>(x)[i];
    ushort4 u;
    u.x = f2b(v.x); u.y = f2b(v.y); u.z = f2b(v.z); u.w = f2b(v.w);
    reinterpret_cast<ushort4*>(x_bf)[i] = u;
  } else if (blk < 19456) {
    permute_w_dev(Wf0, pf0, (long)(blk - 16384) * 256 + tid, 1024);
  } else if (blk < 22528) {
    permute_w_dev(Wb0, pb0, (long)(blk - 19456) * 256 + tid, 1024);
  } else if (blk < 28672) {
    permute_w_dev(Wf1, pf1, (long)(blk - 22528) * 256 + tid, 2048);
  } else if (blk < 34816) {
    permute_w_dev(Wb1, pb1, (long)(blk - 28672) * 256 + tid, 2048);
  } else {                         // biases: np = chunk*48 + gate3*16 + hl
    const int r = blk - 34816;     // 0..47
    const int which = r / 12;
    const int np = (r % 12) * 256 + tid;
    const float* bs = which == 0 ? bf0 : which == 1 ? bb0 : which == 2 ? bf1 : bb1;
    float* bd       = which == 0 ? bpf0 : which == 1 ? bpb0 : which == 2 ? bpf1 : bpb1;
    const int chunk = np / 48, rem = np % 48;
    const int g3 = rem >> 4, hl = rem & 15;
    const int og = (g3 == 0) ? 0 : (g3 == 1) ? 2 : 3;
    bd[np] = bs[og * 1024 + chunk * 16 + hl];
  }
}

// ---- fused GEMM + gates, single-phase double-buffered (R3-verified).
//  C = A[M,K] * Wp[NP,K]^T.  Block tile 128x192, BK=64, 256 thr (4 waves 2Mx2N).
//  Wave tile 64x96 = 4 m-frags x 6 n-frags (2 h-chunks x {i,g,o}) = 48 MFMA/tile.
//  LDS: 2 buffers x 40KB (A 128x64 @0, B 192x64 @16384) = 80KB -> 2 blocks/CU.
//  K-loop: STAGE(t+1) early -> 20 ds_reads -> 48 MFMA -> vmcnt(0) -> 1 barrier.
//  XCD-swizzled grid: each XCD walks all 16 bn of one bm (A-panel L2-resident).
template <int MODE>  // 0: layer0 (bf16 out), 1: layer1 (fp32 out to d_out)
__global__ void __launch_bounds__(256, 2)
lstm_gemm(const unsigned short* __restrict__ A,
          const unsigned short* __restrict__ WpF,
          const unsigned short* __restrict__ WpB,
          const float* __restrict__ bpF, const float* __restrict__ bpB,
          int K,
          unsigned short* __restrict__ out_bf, float* __restrict__ out_f,
          float* __restrict__ hn, float* __restrict__ cn) {
  __shared__ __align__(16) char lds[81920];

  const int dir = blockIdx.z;
  const unsigned short* __restrict__ Wp = dir ? WpB : WpF;
  const float* __restrict__ bp = dir ? bpB : bpF;

  // Bijective XCD swizzle (2048 blocks per z; xcd = flat % 8 round-robin):
  // XCD q gets virt ids q*256..q*256+255, walking bn fastest within one bm.
  const int f    = blockIdx.x + (blockIdx.y << 4);    // 0..2047
  const int virt = (f >> 3) + (f & 7) * 256;
  const int bm   = virt >> 4;    // 0..127 (128-row band of A)
  const int bn   = virt & 15;    // 0..15  (192-col band of Wp)

  const int tid  = threadIdx.x;
  const int wid  = tid >> 6;
  const int lane = tid & 63;
  const int wm   = wid >> 1;   // 0..1
  const int wn   = wid & 1;    // 0..1

  const int  nt = K >> 6;
  const long K2 = (long)K * 2;

  // ---- staging constants (linear LDS dest, pre-swizzled global source).
  //  Slot = 8 rows x 128B = 1KB, written by one global_load_lds of one wave.
  //  LDS (row, c16) holds global (row, c16 ^ (row&7)).
  const int rlane = lane >> 3;                       // row within slot 0..7
  const int cb    = (((lane & 7) ^ rlane) << 4);     // pre-swizzled col byte
  const char* Asrc = (const char*)A  + ((long)bm * 128 + rlane) * K2 + cb;
  const char* Bsrc = (const char*)Wp + ((long)bn * 192 + rlane) * K2 + cb;

  // ---- compute-side constants (swizzled ds_read) ----
  const int l15 = lane & 15;
  const int hi  = lane >> 4;                  // 0..3
  const int c0  = ((hi ^ (l15 & 7)) << 4);    // kh0 chunk; kh1 = c0 ^ 64
  const int aro = (wm * 64 + l15) * 128;            // + mf*2048
  const int bro = 16384 + (wn * 96 + l15) * 128;    // + nf*2048

  f32x4 acc[4][6];
  const f32x4 zero = {0.f, 0.f, 0.f, 0.f};
#pragma unroll
  for (int i = 0; i < 4; ++i)
#pragma unroll
    for (int j = 0; j < 6; ++j) acc[i][j] = zero;

  auto STAGE = [&](int t) {   // 10 x global_load_lds per thread
    if (t >= nt) return;
    char* d = lds + (t & 1) * 40960;
    const long off = (long)t * 128;   // 64 bf16 = 128 B per K-tile
#pragma unroll
    for (int s = 0; s < 4; ++s) {
      const int slot = s * 4 + wid;   // 0..15 -> A rows slot*8..slot*8+7
      load_lds16(Asrc + (long)(slot * 8) * K2 + off, d + slot * 1024);
    }
#pragma unroll
    for (int s = 0; s < 6; ++s) {
      const int slot = s * 4 + wid;   // 0..23 -> B rows slot*8..slot*8+7
      load_lds16(Bsrc + (long)(slot * 8) * K2 + off, d + 16384 + slot * 1024);
    }
  };

  STAGE(0);
  asm volatile("s_waitcnt vmcnt(0)" ::: "memory");
  BARRIER;

  for (int t = 0; t < nt; ++t) {
    STAGE(t + 1);   // issue early; latency hidden under reads + MFMA below

    const char* buf = lds + (t & 1) * 40960;
    bf16x8 a[4][2], b[6][2];
#pragma unroll
    for (int nf = 0; nf < 6; ++nf) {
      b[nf][0] = *(const bf16x8*)(buf + bro + nf * 2048 + c0);
      b[nf][1] = *(const bf16x8*)(buf + bro + nf * 2048 + (c0 ^ 64));
    }
#pragma unroll
    for (int mf = 0; mf < 4; ++mf) {
      a[mf][0] = *(const bf16x8*)(buf + aro + mf * 2048 + c0);
      a[mf][1] = *(const bf16x8*)(buf + aro + mf * 2048 + (c0 ^ 64));
    }

    __builtin_amdgcn_s_setprio(1);
#pragma unroll
    for (int mf = 0; mf < 4; ++mf)
#pragma unroll
      for (int nf = 0; nf < 6; ++nf) {
        acc[mf][nf] = __builtin_amdgcn_mfma_f32_16x16x32_bf16(
            a[mf][0], b[nf][0], acc[mf][nf], 0, 0, 0);
        acc[mf][nf] = __builtin_amdgcn_mfma_f32_16x16x32_bf16(
            a[mf][1], b[nf][1], acc[mf][nf], 0, 0, 0);
      }
    __builtin_amdgcn_s_setprio(0);

    // all iter-t ds_reads completed (consumed by MFMAs above); drain stage
    // loads so buf[(t+1)&1] is fully written before next iter reads it.
    asm volatile("s_waitcnt vmcnt(0)" ::: "memory");
    BARRIER;
  }

  // ---- epilogue: gates -> h (and h_n/c_n rows) ----
  const int col    = l15;
  const int rbase  = hi * 4;
  const int chunk0 = bn * 4 + wn * 2;
  const int Lidx   = MODE * 2 + dir;

#pragma unroll
  for (int hg = 0; hg < 2; ++hg) {
    const int chunk  = chunk0 + hg;
    const int h      = chunk * 16 + col;
    const int outcol = dir * HID + h;
    const float bi = bp[chunk * 48 + col];
    const float bg = bp[chunk * 48 + 16 + col];
    const float bo = bp[chunk * 48 + 32 + col];
#pragma unroll
    for (int mf = 0; mf < 4; ++mf) {
#pragma unroll
      for (int r = 0; r < 4; ++r) {
        const int m = bm * 128 + wm * 64 + mf * 16 + rbase + r;
        const float iv = acc[mf][hg * 3 + 0][r] + bi;
        const float gv = acc[mf][hg * 3 + 1][r] + bg;
        const float ov = acc[mf][hg * 3 + 2][r] + bo;
        const float is = sigf(iv);
        const float gt = tanh_f(gv);
        const float os = sigf(ov);
        const float c  = is * gt;
        const float hv = os * tanh_f(c);
        if (MODE == 0) {
          out_bf[(long)m * 2048 + outcol] = f2b(hv);
        } else {
          out_f[(long)m * 2048 + outcol] = hv;
        }
        const bool wst = (dir == 0) ? (m >= (S_LEN - 1) * BATCH) : (m < BATCH);
        if (wst) {
          const int b = (dir == 0) ? (m - (S_LEN - 1) * BATCH) : m;
          hn[((long)Lidx * BATCH + b) * HID + h] = hv;
          cn[((long)Lidx * BATCH + b) * HID + h] = c;
        }
      }
    }
  }
}

extern "C" void kernel_launch(void* const* d_in, const int* in_sizes, int n_in,
                              void* d_out, int out_size, void* d_ws, size_t ws_size,
                              hipStream_t stream) {
  const float* x    = (const float*)d_in[0];
  const float* W_f0 = (const float*)d_in[1];
  const float* b_f0 = (const float*)d_in[2];
  const float* W_b0 = (const float*)d_in[3];
  const float* b_b0 = (const float*)d_in[4];
  const float* W_f1 = (const float*)d_in[5];
  const float* b_f1 = (const float*)d_in[6];
  const float* W_b1 = (const float*)d_in[7];
  const float* b_b1 = (const float*)d_in[8];

  float* out = (float*)d_out;
  float* hn  = out + (long)MROWS * 2048;
  float* cn  = hn + 4 * BATCH * HID;

  unsigned short* x_bf  = (unsigned short*)d_ws;
  unsigned short* out1  = x_bf + (long)MROWS * 1024;
  unsigned short* wp_f0 = out1 + (long)MROWS * 2048;
  unsigned short* wp_b0 = wp_f0 + (long)NP * 1024;
  unsigned short* wp_f1 = wp_b0 + (long)NP * 1024;
  unsigned short* wp_b1 = wp_f1 + (long)NP * 2048;
  float* bp_f0 = (float*)(wp_b1 + (long)NP * 2048);
  float* bp_b0 = bp_f0 + NP;
  float* bp_f1 = bp_b0 + NP;
  float* bp_b1 = bp_f1 + NP;

  prep<<<34864, 256, 0, stream>>>(x, x_bf, W_f0, W_b0, W_f1, W_b1,
                                  wp_f0, wp_b0, wp_f1, wp_b1,
                                  b_f0, b_b0, b_f1, b_b1,
                                  bp_f0, bp_b0, bp_f1, bp_b1);

  dim3 grid(16, 128, 2);
  lstm_gemm<0><<<grid, 256, 0, stream>>>(x_bf, wp_f0, wp_b0, bp_f0, bp_b0, 1024,
                                         out1, nullptr, hn, cn);
  lstm_gemm<1><<<grid, 256, 0, stream>>>(out1, wp_f1, wp_b1, bp_f1, bp_b1, 2048,
                                         nullptr, out, hn, cn);
}